// Round 6
// baseline (245.821 us; speedup 1.0000x reference)
//
#include <hip/hip_runtime.h>

#define NROWS 8192
#define DDIM  1024           // elements per row (fp8: also bytes per row)
#define BM 128
#define BN 128
#define BKB 128              // K-bytes per tile iteration (128 fp8 elements)
#define NSTRIPES 16
#define CT_PER_STRIPE 4      // 8192 / (128*16)
#define MARGIN_F 0.05f
#define FP8_SCALE 8.0f       // power of 2; sims are scaled by 64 in mining space

typedef __attribute__((ext_vector_type(8)))  int   int8v;
typedef __attribute__((ext_vector_type(4)))  int   int4v;
typedef __attribute__((ext_vector_type(16))) float floatx16;

__device__ __forceinline__ void g2lds16(const void* g, void* l) {
  __builtin_amdgcn_global_load_lds(
      (const __attribute__((address_space(1))) void*)g,
      (__attribute__((address_space(3))) void*)l, 16, 0, 0);
}

// Monotonic packing: larger sim wins; exact tie -> smaller column index
// (matches jnp.argmax first-occurrence).
__device__ __forceinline__ unsigned long long pack_key(float v, int j) {
  unsigned int u = __float_as_uint(v);
  u = (u & 0x80000000u) ? ~u : (u | 0x80000000u);
  return ((unsigned long long)u << 32) | (unsigned long long)(0x7FFFFFFFu - (unsigned int)j);
}

// One block per row: exact fp32 pos_sim, fp32 -> fp8(e4m3, x8 scaled) quantize
// of x and y, zero the key array, zero out[0] (ws/out poisoned 0xAA each call).
__global__ void prep_kernel(const float* __restrict__ x, const float* __restrict__ y,
                            unsigned int* __restrict__ xq, unsigned int* __restrict__ yq,
                            float* __restrict__ pos, unsigned long long* __restrict__ keys,
                            float* __restrict__ out) {
  const int row = blockIdx.x;
  const int t = threadIdx.x;  // 256 threads, one float4 each (D=1024)
  const float4 a = ((const float4*)(x + (size_t)row * DDIM))[t];
  const float4 b = ((const float4*)(y + (size_t)row * DDIM))[t];
  float s = a.x * b.x + a.y * b.y + a.z * b.z + a.w * b.w;

  int pa = __builtin_amdgcn_cvt_pk_fp8_f32(a.x * FP8_SCALE, a.y * FP8_SCALE, 0, false);
  pa     = __builtin_amdgcn_cvt_pk_fp8_f32(a.z * FP8_SCALE, a.w * FP8_SCALE, pa, true);
  int pb = __builtin_amdgcn_cvt_pk_fp8_f32(b.x * FP8_SCALE, b.y * FP8_SCALE, 0, false);
  pb     = __builtin_amdgcn_cvt_pk_fp8_f32(b.z * FP8_SCALE, b.w * FP8_SCALE, pb, true);
  xq[(size_t)row * 256 + t] = (unsigned int)pa;
  yq[(size_t)row * 256 + t] = (unsigned int)pb;

  for (int m = 32; m; m >>= 1) s += __shfl_down(s, m, 64);
  __shared__ float ps[4];
  if ((t & 63) == 0) ps[t >> 6] = s;
  __syncthreads();
  if (t == 0) {
    pos[row] = ps[0] + ps[1] + ps[2] + ps[3];
    keys[row] = 0ULL;
    if (row == 0) out[0] = 0.f;
  }
}

// MX-fp8 (K=64 per MFMA, unit scales) 32x32x64 MFMA GEMM tile + mask +
// row-argmax, merged globally via atomicMax on packed (value,index) keys.
// Wave tiling 1x4 (40 fragment regs + 64 acc). launch_bounds(256,3):
// per-wave unified budget ~170 >= measured demand 100 VGPR + 64 AGPR = 164.
// (256,2) measured latency-bound at 21% occupancy (MfmaUtil 19, VALU 24);
// 3 blocks/CU is the m97-class operating point.
__global__ __launch_bounds__(256, 3) void mine_kernel(
    const unsigned char* __restrict__ xq, const unsigned char* __restrict__ yq,
    const float* __restrict__ pos, unsigned long long* __restrict__ keys) {
  __shared__ unsigned char As[BM * BKB];  // 16 KB, XOR-swizzled
  __shared__ unsigned char Bs[BN * BKB];  // 16 KB, XOR-swizzled
  __shared__ float pos_s[BM];

  const int t = threadIdx.x;
  const int rowBase = blockIdx.x * BM;
  const int stripe  = blockIdx.y;
  if (t < BM) pos_s[t] = pos[rowBase + t] * (FP8_SCALE * FP8_SCALE);

  const int lane = t & 63;
  const int wave = t >> 6;
  const int r31  = lane & 31;     // row-in-tile (A) / col-in-tile (B)
  const int kh   = lane >> 5;     // K-half selector
  // Swizzle: chunk c (16B) of LDS row r lives at position c^(r&7).
  // Fragment k-chunks for (ks,kh): p0 = 4*ks + 2*kh, p0+1. Since 32|rowstep,
  // (r&7) == (r31&7) for every tile this lane touches -> one base offset;
  // ks toggles bit6 (^64), the second chunk toggles bit4 (^16).
  const int fragBase = r31 * BKB + (((2 * kh) ^ (r31 & 7)) << 4);
  const int offA = wave * (32 * BKB) + fragBase;

  for (int ct = 0; ct < CT_PER_STRIPE; ++ct) {
    const int colBase = stripe * (BN * CT_PER_STRIPE) + ct * BN;

    floatx16 acc[4];
#pragma unroll
    for (int ni = 0; ni < 4; ++ni)
#pragma unroll
      for (int r = 0; r < 16; ++r) acc[ni][r] = 0.f;

    for (int k0 = 0; k0 < DDIM; k0 += BKB) {
      __syncthreads();  // previous iteration's ds_reads done before overwrite
      // Stage A and B tiles via global_load_lds width=16.
      // 1024 chunks (16 B) per tile; 4 issues per thread per tile.
      // LDS dest is wave-uniform base + lane*16; swizzle carried by the
      // per-lane global source address.
#pragma unroll
      for (int i = 0; i < 4; ++i) {
        const int c  = i * 256 + t;          // chunk id this lane fills
        const int r  = c >> 3;               // tile row 0..127
        const int sw = (c & 7) ^ (r & 7);    // swizzled source chunk in row
        const unsigned char* gA = xq + (size_t)(rowBase + r) * DDIM + k0 + sw * 16;
        const unsigned char* gB = yq + (size_t)(colBase + r) * DDIM + k0 + sw * 16;
        unsigned char* lA = &As[(size_t)(i * 256 + wave * 64) * 16];
        unsigned char* lB = &Bs[(size_t)(i * 256 + wave * 64) * 16];
        g2lds16(gA, lA);
        g2lds16(gB, lB);
      }
      __syncthreads();

#pragma unroll
      for (int ks = 0; ks < 2; ++ks) {
        const int kx = ks << 6;  // ^64 selects the second K-64 of the tile
        int4v alo = *(const int4v*)&As[offA ^ kx];
        int4v ahi = *(const int4v*)&As[(offA ^ kx) ^ 16];
        int8v af = __builtin_shufflevector(alo, ahi, 0, 1, 2, 3, 4, 5, 6, 7);
#pragma unroll
        for (int ni = 0; ni < 4; ++ni) {
          const int offB = ni * (32 * BKB) + fragBase;
          int4v blo = *(const int4v*)&Bs[offB ^ kx];
          int4v bhi = *(const int4v*)&Bs[(offB ^ kx) ^ 16];
          int8v bf = __builtin_shufflevector(blo, bhi, 0, 1, 2, 3, 4, 5, 6, 7);
          acc[ni] = __builtin_amdgcn_mfma_scale_f32_32x32x64_f8f6f4(
              af, bf, acc[ni], 0, 0,   // cbsz=0 (fp8), blgp=0 (fp8)
              0, 0x7F7F7F7F,           // opsel_a, scale_a = 1.0 (E8M0)
              0, 0x7F7F7F7F);          // opsel_b, scale_b = 1.0
        }
      }
    }

    // Epilogue: mask (diag, sim > pos) in x64-scaled space, row-wise
    // (max, min-index) reduce across the 32 lanes holding each row.
    // 32x32 C/D layout (HW-verified): col = lane&31,
    // row = (reg&3) + 8*(reg>>2) + 4*(lane>>5).
#pragma unroll
    for (int reg = 0; reg < 16; ++reg) {
      const int row_l = 32 * wave + (reg & 3) + 8 * (reg >> 2) + 4 * kh;
      const int row_g = rowBase + row_l;
      const float p = pos_s[row_l];
      float bestv = -1.0e30f; int bestj = 0;
#pragma unroll
      for (int ni = 0; ni < 4; ++ni) {
        float v = acc[ni][reg];
        const int col_g = colBase + 32 * ni + r31;
        if (col_g == row_g || v > p) v = -1024.0f;  // below any valid scaled sim
        if (v > bestv || (v == bestv && col_g < bestj)) { bestv = v; bestj = col_g; }
      }
      unsigned long long key = pack_key(bestv, bestj);
#pragma unroll
      for (int m = 1; m <= 16; m <<= 1) {
        unsigned long long o = __shfl_xor(key, m, 64);
        if (o > key) key = o;
      }
      if (r31 == 0) atomicMax(&keys[row_g], key);
    }
  }
}

// Exact fp32 recompute of neg_sim for the mined index + loss reduction.
// 256 blocks x 256 threads; each wave handles 8 rows; partials atomicAdd'ed
// into out[0] (zeroed by prep, stream-ordered).
__global__ void final_kernel(const float* __restrict__ x, const float* __restrict__ y,
                             const float* __restrict__ pos,
                             const unsigned long long* __restrict__ keys,
                             float* __restrict__ out) {
  const int t = threadIdx.x;
  const int lane = t & 63, wave = t >> 6;
  float accl = 0.f;
#pragma unroll
  for (int i = 0; i < 8; ++i) {
    const int row = blockIdx.x * 32 + i * 4 + wave;
    const unsigned long long k = keys[row];
    const int j = 0x7FFFFFFF - (int)(k & 0xFFFFFFFFULL);
    const float4* xr = (const float4*)(x + (size_t)row * DDIM);
    const float4* yr = (const float4*)(y + (size_t)j * DDIM);
    float s = 0.f;
#pragma unroll
    for (int u = 0; u < 4; ++u) {
      const float4 a = xr[lane + 64 * u];
      const float4 b = yr[lane + 64 * u];
      s += a.x * b.x + a.y * b.y + a.z * b.z + a.w * b.w;
    }
    for (int m = 32; m; m >>= 1) s += __shfl_down(s, m, 64);
    if (lane == 0) {
      const float l = MARGIN_F - pos[row] + s;
      accl += l > 0.f ? l : 0.f;
    }
  }
  __shared__ float ps[4];
  if (lane == 0) ps[wave] = accl;
  __syncthreads();
  if (t == 0) atomicAdd(out, (ps[0] + ps[1] + ps[2] + ps[3]) * (1.0f / (float)NROWS));
}

extern "C" void kernel_launch(void* const* d_in, const int* in_sizes, int n_in,
                              void* d_out, int out_size, void* d_ws, size_t ws_size,
                              hipStream_t stream) {
  const float* x = (const float*)d_in[0];
  const float* y = (const float*)d_in[1];
  float* out = (float*)d_out;

  // ws layout: keys 64 KB | pos 32 KB | xq 8 MB | yq 8 MB  (~16.1 MB)
  unsigned long long* keys = (unsigned long long*)d_ws;
  float* pos = (float*)((char*)d_ws + (size_t)NROWS * 8);
  unsigned char* xq = (unsigned char*)d_ws + (size_t)NROWS * 8 + (size_t)NROWS * 4;
  unsigned char* yq = xq + (size_t)NROWS * DDIM;

  prep_kernel<<<NROWS, 256, 0, stream>>>(x, y, (unsigned int*)xq, (unsigned int*)yq,
                                         pos, keys, out);
  dim3 grid(NROWS / BM, NSTRIPES);
  mine_kernel<<<grid, 256, 0, stream>>>(xq, yq, pos, keys);
  final_kernel<<<NROWS / 32, 256, 0, stream>>>(x, y, pos, keys, out);
}

// Round 7
// 221.703 us; speedup vs baseline: 1.1088x; 1.1088x over previous
//
#include <hip/hip_runtime.h>

#define NROWS 8192
#define DDIM  1024           // elements per row (fp8: also bytes per row)
#define BM 128
#define BN 256
#define BKB 128              // K-bytes per tile iteration (128 fp8 elements)
#define NSTRIPES 8
#define CT_PER_STRIPE 4      // 8192 / (256*8)
#define MARGIN_F 0.05f
#define FP8_SCALE 8.0f       // power of 2; sims are scaled by 64 in mining space

typedef __attribute__((ext_vector_type(8)))  int   int8v;
typedef __attribute__((ext_vector_type(4)))  int   int4v;
typedef __attribute__((ext_vector_type(16))) float floatx16;

__device__ __forceinline__ void g2lds16(const void* g, void* l) {
  __builtin_amdgcn_global_load_lds(
      (const __attribute__((address_space(1))) void*)g,
      (__attribute__((address_space(3))) void*)l, 16, 0, 0);
}

// Monotonic packing: larger sim wins; exact tie -> smaller column index
// (matches jnp.argmax first-occurrence).
__device__ __forceinline__ unsigned long long pack_key(float v, int j) {
  unsigned int u = __float_as_uint(v);
  u = (u & 0x80000000u) ? ~u : (u | 0x80000000u);
  return ((unsigned long long)u << 32) | (unsigned long long)(0x7FFFFFFFu - (unsigned int)j);
}

// One block per row: exact fp32 pos_sim, fp32 -> fp8(e4m3, x8 scaled) quantize
// of x and y, zero the key array, zero out[0] (ws/out poisoned 0xAA each call).
__global__ void prep_kernel(const float* __restrict__ x, const float* __restrict__ y,
                            unsigned int* __restrict__ xq, unsigned int* __restrict__ yq,
                            float* __restrict__ pos, unsigned long long* __restrict__ keys,
                            float* __restrict__ out) {
  const int row = blockIdx.x;
  const int t = threadIdx.x;  // 256 threads, one float4 each (D=1024)
  const float4 a = ((const float4*)(x + (size_t)row * DDIM))[t];
  const float4 b = ((const float4*)(y + (size_t)row * DDIM))[t];
  float s = a.x * b.x + a.y * b.y + a.z * b.z + a.w * b.w;

  int pa = __builtin_amdgcn_cvt_pk_fp8_f32(a.x * FP8_SCALE, a.y * FP8_SCALE, 0, false);
  pa     = __builtin_amdgcn_cvt_pk_fp8_f32(a.z * FP8_SCALE, a.w * FP8_SCALE, pa, true);
  int pb = __builtin_amdgcn_cvt_pk_fp8_f32(b.x * FP8_SCALE, b.y * FP8_SCALE, 0, false);
  pb     = __builtin_amdgcn_cvt_pk_fp8_f32(b.z * FP8_SCALE, b.w * FP8_SCALE, pb, true);
  xq[(size_t)row * 256 + t] = (unsigned int)pa;
  yq[(size_t)row * 256 + t] = (unsigned int)pb;

  for (int m = 32; m; m >>= 1) s += __shfl_down(s, m, 64);
  __shared__ float ps[4];
  if ((t & 63) == 0) ps[t >> 6] = s;
  __syncthreads();
  if (t == 0) {
    pos[row] = ps[0] + ps[1] + ps[2] + ps[3];
    keys[row] = 0ULL;
    if (row == 0) out[0] = 0.f;
  }
}

// MX-fp8 (K=64 per MFMA, unit scales) 32x32x64 MFMA GEMM tile + mask +
// row-argmax, merged globally via atomicMax on packed (value,index) keys.
// 128x256 block tile, 4 waves in 2x2; each wave = 64 rows x 128 cols =
// 2 A-frags x 4 B-frags -> 8 MFMA per 12 b128 reads (24 B/lane/MFMA, vs 40
// in the 1x4 shape). R5/R6 measured LDS-read-throughput bound (82 us of LDS
// unit time vs 29 us MFMA floor); this cuts LDS bytes/FLOP by 40%.
__global__ __launch_bounds__(256, 2) void mine_kernel(
    const unsigned char* __restrict__ xq, const unsigned char* __restrict__ yq,
    const float* __restrict__ pos, unsigned long long* __restrict__ keys) {
  __shared__ unsigned char As[BM * BKB];  // 16 KB, XOR-swizzled
  __shared__ unsigned char Bs[BN * BKB];  // 32 KB, XOR-swizzled
  __shared__ float pos_s[BM];

  const int t = threadIdx.x;
  const int rowBase = blockIdx.x * BM;
  const int stripe  = blockIdx.y;
  if (t < BM) pos_s[t] = pos[rowBase + t] * (FP8_SCALE * FP8_SCALE);

  const int lane = t & 63;
  const int wave = t >> 6;
  const int wr = wave >> 1, wc = wave & 1;
  const int r31  = lane & 31;     // row-in-tile (A) / col-in-tile (B)
  const int kh   = lane >> 5;     // K-half selector
  // Swizzle: chunk c (16B) of LDS row r lives at position c^(r&7); 32|rowstep
  // so (row&7)==(r31&7) for every tile this lane touches. ks toggles byte-
  // offset bit6 (^64); the pair's second chunk toggles bit4 (^16).
  const int fragOff = ((2 * kh) ^ (r31 & 7)) << 4;
  const int offA0 = (64 * wr + r31) * BKB + fragOff;       // mi adds 32*BKB
  const int offB0 = (128 * wc + r31) * BKB + fragOff;      // ni adds 32*BKB

  for (int ct = 0; ct < CT_PER_STRIPE; ++ct) {
    const int colBase = stripe * (BN * CT_PER_STRIPE) + ct * BN;

    floatx16 acc[2][4];
#pragma unroll
    for (int mi = 0; mi < 2; ++mi)
#pragma unroll
      for (int ni = 0; ni < 4; ++ni)
#pragma unroll
        for (int r = 0; r < 16; ++r) acc[mi][ni][r] = 0.f;

    for (int k0 = 0; k0 < DDIM; k0 += BKB) {
      __syncthreads();  // previous iteration's ds_reads done before overwrite
      // Stage A (16 KB, 4 issues/thread) and B (32 KB, 8 issues/thread) via
      // global_load_lds width=16. LDS dest is wave-uniform base + lane*16;
      // the swizzle is carried by the per-lane global source address.
#pragma unroll
      for (int i = 0; i < 4; ++i) {
        const int c  = i * 256 + t;
        const int r  = c >> 3;               // 0..127
        const int sw = (c & 7) ^ (r & 7);
        g2lds16(xq + (size_t)(rowBase + r) * DDIM + k0 + sw * 16,
                &As[(size_t)(i * 256 + wave * 64) * 16]);
      }
#pragma unroll
      for (int i = 0; i < 8; ++i) {
        const int c  = i * 256 + t;
        const int r  = c >> 3;               // 0..255
        const int sw = (c & 7) ^ (r & 7);
        g2lds16(yq + (size_t)(colBase + r) * DDIM + k0 + sw * 16,
                &Bs[(size_t)(i * 256 + wave * 64) * 16]);
      }
      __syncthreads();

#pragma unroll
      for (int ks = 0; ks < 2; ++ks) {
        const int kx = ks << 6;  // ^64 selects the second K-64 of the tile
        int8v af[2];
#pragma unroll
        for (int mi = 0; mi < 2; ++mi) {
          const int oA = (offA0 + mi * 32 * BKB) ^ kx;
          int4v lo = *(const int4v*)&As[oA];
          int4v hi = *(const int4v*)&As[oA ^ 16];
          af[mi] = __builtin_shufflevector(lo, hi, 0, 1, 2, 3, 4, 5, 6, 7);
        }
#pragma unroll
        for (int ni = 0; ni < 4; ++ni) {
          const int oB = (offB0 + ni * 32 * BKB) ^ kx;
          int4v blo = *(const int4v*)&Bs[oB];
          int4v bhi = *(const int4v*)&Bs[oB ^ 16];
          int8v bf = __builtin_shufflevector(blo, bhi, 0, 1, 2, 3, 4, 5, 6, 7);
          acc[0][ni] = __builtin_amdgcn_mfma_scale_f32_32x32x64_f8f6f4(
              af[0], bf, acc[0][ni], 0, 0, 0, 0x7F7F7F7F, 0, 0x7F7F7F7F);
          acc[1][ni] = __builtin_amdgcn_mfma_scale_f32_32x32x64_f8f6f4(
              af[1], bf, acc[1][ni], 0, 0, 0, 0x7F7F7F7F, 0, 0x7F7F7F7F);
        }
      }
    }

    // Epilogue: mask (diag, sim > pos) in x64-scaled space, row-wise
    // (max, min-index) reduce across the 32 lanes holding each row.
    // 32x32 C/D layout (HW-verified): col = lane&31,
    // row = (reg&3) + 8*(reg>>2) + 4*(lane>>5).
#pragma unroll
    for (int mi = 0; mi < 2; ++mi) {
#pragma unroll
      for (int reg = 0; reg < 16; ++reg) {
        const int row_l = 64 * wr + 32 * mi + (reg & 3) + 8 * (reg >> 2) + 4 * kh;
        const int row_g = rowBase + row_l;
        const float p = pos_s[row_l];
        float bestv = -1.0e30f; int bestj = 0;
#pragma unroll
        for (int ni = 0; ni < 4; ++ni) {
          float v = acc[mi][ni][reg];
          const int col_g = colBase + 128 * wc + 32 * ni + r31;
          if (col_g == row_g || v > p) v = -1024.0f;  // below any valid scaled sim
          if (v > bestv || (v == bestv && col_g < bestj)) { bestv = v; bestj = col_g; }
        }
        unsigned long long key = pack_key(bestv, bestj);
#pragma unroll
        for (int m = 1; m <= 16; m <<= 1) {
          unsigned long long o = __shfl_xor(key, m, 64);
          if (o > key) key = o;
        }
        if (r31 == 0) atomicMax(&keys[row_g], key);
      }
    }
  }
}

// Exact fp32 recompute of neg_sim for the mined index + loss reduction.
// 256 blocks x 256 threads; each wave handles 8 rows; partials atomicAdd'ed
// into out[0] (zeroed by prep, stream-ordered).
__global__ void final_kernel(const float* __restrict__ x, const float* __restrict__ y,
                             const float* __restrict__ pos,
                             const unsigned long long* __restrict__ keys,
                             float* __restrict__ out) {
  const int t = threadIdx.x;
  const int lane = t & 63, wave = t >> 6;
  float accl = 0.f;
#pragma unroll
  for (int i = 0; i < 8; ++i) {
    const int row = blockIdx.x * 32 + i * 4 + wave;
    const unsigned long long k = keys[row];
    const int j = 0x7FFFFFFF - (int)(k & 0xFFFFFFFFULL);
    const float4* xr = (const float4*)(x + (size_t)row * DDIM);
    const float4* yr = (const float4*)(y + (size_t)j * DDIM);
    float s = 0.f;
#pragma unroll
    for (int u = 0; u < 4; ++u) {
      const float4 a = xr[lane + 64 * u];
      const float4 b = yr[lane + 64 * u];
      s += a.x * b.x + a.y * b.y + a.z * b.z + a.w * b.w;
    }
    for (int m = 32; m; m >>= 1) s += __shfl_down(s, m, 64);
    if (lane == 0) {
      const float l = MARGIN_F - pos[row] + s;
      accl += l > 0.f ? l : 0.f;
    }
  }
  __shared__ float ps[4];
  if (lane == 0) ps[wave] = accl;
  __syncthreads();
  if (t == 0) atomicAdd(out, (ps[0] + ps[1] + ps[2] + ps[3]) * (1.0f / (float)NROWS));
}

extern "C" void kernel_launch(void* const* d_in, const int* in_sizes, int n_in,
                              void* d_out, int out_size, void* d_ws, size_t ws_size,
                              hipStream_t stream) {
  const float* x = (const float*)d_in[0];
  const float* y = (const float*)d_in[1];
  float* out = (float*)d_out;

  // ws layout: keys 64 KB | pos 32 KB | xq 8 MB | yq 8 MB  (~16.1 MB)
  unsigned long long* keys = (unsigned long long*)d_ws;
  float* pos = (float*)((char*)d_ws + (size_t)NROWS * 8);
  unsigned char* xq = (unsigned char*)d_ws + (size_t)NROWS * 8 + (size_t)NROWS * 4;
  unsigned char* yq = xq + (size_t)NROWS * DDIM;

  prep_kernel<<<NROWS, 256, 0, stream>>>(x, y, (unsigned int*)xq, (unsigned int*)yq,
                                         pos, keys, out);
  dim3 grid(NROWS / BM, NSTRIPES);
  mine_kernel<<<grid, 256, 0, stream>>>(xq, yq, pos, keys);
  final_kernel<<<NROWS / 32, 256, 0, stream>>>(x, y, pos, keys, out);
}